// Round 15
// baseline (113.026 us; speedup 1.0000x reference)
//
#include <hip/hip_runtime.h>

#define NB_CAT  8192
#define RANK    16
#define N_COLS  4
#define N_PAIRS 1048576

#define SLICE_ROWS  NB_CAT
#define SLICE_BYTES (SLICE_ROWS * 16)               // 128 KB: 8192 rows x 16 fp8
#define TBL_BYTES   ((size_t)N_COLS * SLICE_BYTES)  // 512 KB
#define LDS_BYTES   SLICE_BYTES                     // single 128 KB buffer

#if defined(__has_builtin)
#if __has_builtin(__builtin_amdgcn_cvt_pk_f32_fp8) && __has_builtin(__builtin_amdgcn_cvt_pk_fp8_f32)
#define HAVE_FP8 1
#endif
#endif

typedef float float2v __attribute__((ext_vector_type(2)));
typedef _Float16 half2_t __attribute__((ext_vector_type(2)));

template <int C> __device__ __forceinline__ int comp(const int4& v) {
    if (C == 0) return v.x;
    if (C == 1) return v.y;
    if (C == 2) return v.z;
    return v.w;
}

#ifdef HAVE_FP8
// ---------- fp8 path: one 16-B row = whole rank-16 vector ----------

__device__ __forceinline__ float dot16_fp8(uint4 A, uint4 B, float acc) {
#define TERM(u, v, sel)                                                        \
    {                                                                          \
        float2v a = __builtin_amdgcn_cvt_pk_f32_fp8((int)(u), sel);            \
        float2v b = __builtin_amdgcn_cvt_pk_f32_fp8((int)(v), sel);            \
        acc = fmaf(a.x, b.x, acc);                                             \
        acc = fmaf(a.y, b.y, acc);                                             \
    }
    TERM(A.x, B.x, false) TERM(A.x, B.x, true)
    TERM(A.y, B.y, false) TERM(A.y, B.y, true)
    TERM(A.z, B.z, false) TERM(A.z, B.z, true)
    TERM(A.w, B.w, false) TERM(A.w, B.w, true)
#undef TERM
    return acc;
}

// prep: fp32 cf -> fp8 e4m3 table, [c][cat] row = 16 B (one thread per row)
__global__ __launch_bounds__(256) void pack_fp8_kernel(
    const float4* __restrict__ src, uint4* __restrict__ dst)
{
    const int r = blockIdx.x * 256 + threadIdx.x;   // c*NB_CAT + k, 32768 rows
    const float4 f0 = src[r * 4 + 0];
    const float4 f1 = src[r * 4 + 1];
    const float4 f2 = src[r * 4 + 2];
    const float4 f3 = src[r * 4 + 3];
    uint4 u;
    int w;
    w = 0;
    w = __builtin_amdgcn_cvt_pk_fp8_f32(f0.x, f0.y, w, false);
    w = __builtin_amdgcn_cvt_pk_fp8_f32(f0.z, f0.w, w, true);
    u.x = (unsigned int)w;
    w = 0;
    w = __builtin_amdgcn_cvt_pk_fp8_f32(f1.x, f1.y, w, false);
    w = __builtin_amdgcn_cvt_pk_fp8_f32(f1.z, f1.w, w, true);
    u.y = (unsigned int)w;
    w = 0;
    w = __builtin_amdgcn_cvt_pk_fp8_f32(f2.x, f2.y, w, false);
    w = __builtin_amdgcn_cvt_pk_fp8_f32(f2.z, f2.w, w, true);
    u.z = (unsigned int)w;
    w = 0;
    w = __builtin_amdgcn_cvt_pk_fp8_f32(f3.x, f3.y, w, false);
    w = __builtin_amdgcn_cvt_pk_fp8_f32(f3.z, f3.w, w, true);
    u.w = (unsigned int)w;
    dst[r] = u;
}

// main: 4 phases (one per col), single buffer, named-reg prefetch (R12/R14
// proven no-spill machinery). Per pair per phase: 2 ds_read_b128 (whole rows)
// + 16 cvt + 16 fma. Half the LDS instructions and half the staging of fp16.
__global__ __launch_bounds__(1024, 1) void IndexKernel_32238024524411_kernel(
    const int4*  __restrict__ x4,
    const int4*  __restrict__ y4,
    const uint4* __restrict__ tbl,   // fp8 table in ws
    const float* __restrict__ stdv,
    float*       __restrict__ out)
{
    extern __shared__ uint4 sh[];    // 8192 rows = 128 KB

    const int tid  = threadIdx.x;
    const int base = blockIdx.x * 4096 + tid;

    int4 xv[4], yv[4];
#pragma unroll
    for (int j = 0; j < 4; ++j) {
        xv[j] = x4[base + j * 1024];
        yv[j] = y4[base + j * 1024];
    }

    float acc[4] = {0.f, 0.f, 0.f, 0.f};

    // diagonal std^2 pre-pass (exact fp32)
#pragma unroll
    for (int j = 0; j < 4; ++j) {
        const int4 a = xv[j], b = yv[j];
        if (a.x == b.x) { const float s = stdv[0 * NB_CAT + a.x]; acc[j] = fmaf(s, s, acc[j]); }
        if (a.y == b.y) { const float s = stdv[1 * NB_CAT + a.y]; acc[j] = fmaf(s, s, acc[j]); }
        if (a.z == b.z) { const float s = stdv[2 * NB_CAT + a.z]; acc[j] = fmaf(s, s, acc[j]); }
        if (a.w == b.w) { const float s = stdv[3 * NB_CAT + a.w]; acc[j] = fmaf(s, s, acc[j]); }
    }

    // stage col-0 slice
#pragma unroll
    for (int it = 0; it < 8; ++it) sh[tid + it * 1024] = tbl[tid + it * 1024];
    asm volatile("s_waitcnt lgkmcnt(0)" ::: "memory");
    __builtin_amdgcn_s_barrier();
    asm volatile("" ::: "memory");

    uint4 t0, t1, t2, t3, t4, t5, t6, t7;   // named prefetch regs (no array)

#define PHASE(S)                                                               \
    {                                                                          \
        constexpr int s = (S);                                                 \
        if (s < N_COLS - 1) {                                                  \
            const uint4* nsrc = tbl + (size_t)(s + 1) * SLICE_ROWS;            \
            t0 = nsrc[tid];             t1 = nsrc[tid + 1024];                 \
            t2 = nsrc[tid + 2 * 1024];  t3 = nsrc[tid + 3 * 1024];             \
            t4 = nsrc[tid + 4 * 1024];  t5 = nsrc[tid + 5 * 1024];             \
            t6 = nsrc[tid + 6 * 1024];  t7 = nsrc[tid + 7 * 1024];             \
        }                                                                      \
        asm volatile("" ::: "memory");                                         \
        _Pragma("unroll")                                                      \
        for (int j = 0; j < 4; ++j) {                                          \
            const int a = comp<s>(xv[j]);                                      \
            const int b = comp<s>(yv[j]);                                      \
            acc[j] = dot16_fp8(sh[a], sh[b], acc[j]);                          \
        }                                                                      \
        if (s < N_COLS - 1) {                                                  \
            asm volatile("s_waitcnt lgkmcnt(0)" ::: "memory");                 \
            __builtin_amdgcn_s_barrier();                                      \
            asm volatile("" ::: "memory");                                     \
            sh[tid]            = t0;  sh[tid + 1024]     = t1;                 \
            sh[tid + 2 * 1024] = t2;  sh[tid + 3 * 1024] = t3;                 \
            sh[tid + 4 * 1024] = t4;  sh[tid + 5 * 1024] = t5;                 \
            sh[tid + 6 * 1024] = t6;  sh[tid + 7 * 1024] = t7;                 \
            asm volatile("s_waitcnt lgkmcnt(0)" ::: "memory");                 \
            __builtin_amdgcn_s_barrier();                                      \
            asm volatile("" ::: "memory");                                     \
        }                                                                      \
    }

    PHASE(0) PHASE(1) PHASE(2) PHASE(3)
#undef PHASE

#pragma unroll
    for (int j = 0; j < 4; ++j) {
        out[base + j * 1024] = acc[j];
    }
}
#endif  // HAVE_FP8

// ---------- fallback (fp32 direct gather, R3 structure) ----------
__global__ __launch_bounds__(256) void fallback_kernel(
    const int* __restrict__ x, const int* __restrict__ y,
    const float4* __restrict__ cf, const float* __restrict__ stdv,
    float* __restrict__ out)
{
    const int tid = threadIdx.x;
    const int q = tid & 15, gi = tid >> 4, c = q >> 2, s = q & 3;
    const int p0 = blockIdx.x * 32 + gi, p1 = p0 + 16;
    const int rb = c * NB_CAT;
    const int xi0 = x[p0*4+c], yi0 = y[p0*4+c], xi1 = x[p1*4+c], yi1 = y[p1*4+c];
    const float4 a0 = cf[(size_t)(rb+xi0)*4 + s], b0 = cf[(size_t)(rb+yi0)*4 + s];
    const float4 a1 = cf[(size_t)(rb+xi1)*4 + s], b1 = cf[(size_t)(rb+yi1)*4 + s];
    float v0 = a0.x*b0.x; v0 = fmaf(a0.y,b0.y,v0); v0 = fmaf(a0.z,b0.z,v0); v0 = fmaf(a0.w,b0.w,v0);
    float v1 = a1.x*b1.x; v1 = fmaf(a1.y,b1.y,v1); v1 = fmaf(a1.z,b1.z,v1); v1 = fmaf(a1.w,b1.w,v1);
    if (s == 0 && xi0 == yi0) { float sd = stdv[rb+xi0]; v0 = fmaf(sd,sd,v0); }
    if (s == 0 && xi1 == yi1) { float sd = stdv[rb+xi1]; v1 = fmaf(sd,sd,v1); }
    int t;
    t = __builtin_amdgcn_update_dpp(0, __float_as_int(v0), 0xB1, 0xF, 0xF, true); v0 += __int_as_float(t);
    t = __builtin_amdgcn_update_dpp(0, __float_as_int(v0), 0x4E, 0xF, 0xF, true); v0 += __int_as_float(t);
    t = __builtin_amdgcn_update_dpp(0, __float_as_int(v0), 0x141,0xF, 0xF, true); v0 += __int_as_float(t);
    t = __builtin_amdgcn_update_dpp(0, __float_as_int(v0), 0x128,0xF, 0xF, true); v0 += __int_as_float(t);
    t = __builtin_amdgcn_update_dpp(0, __float_as_int(v1), 0xB1, 0xF, 0xF, true); v1 += __int_as_float(t);
    t = __builtin_amdgcn_update_dpp(0, __float_as_int(v1), 0x4E, 0xF, 0xF, true); v1 += __int_as_float(t);
    t = __builtin_amdgcn_update_dpp(0, __float_as_int(v1), 0x141,0xF, 0xF, true); v1 += __int_as_float(t);
    t = __builtin_amdgcn_update_dpp(0, __float_as_int(v1), 0x128,0xF, 0xF, true); v1 += __int_as_float(t);
    if (q == 0) { out[p0] = v0; out[p1] = v1; }
}

extern "C" void kernel_launch(void* const* d_in, const int* in_sizes, int n_in,
                              void* d_out, int out_size, void* d_ws, size_t ws_size,
                              hipStream_t stream) {
    const int*   x    = (const int*)d_in[0];
    const int*   y    = (const int*)d_in[1];
    const float* cf   = (const float*)d_in[2];
    const float* stdv = (const float*)d_in[3];
    float*       out  = (float*)d_out;

#ifdef HAVE_FP8
    if (ws_size >= TBL_BYTES) {
        (void)hipFuncSetAttribute(
            reinterpret_cast<const void*>(&IndexKernel_32238024524411_kernel),
            hipFuncAttributeMaxDynamicSharedMemorySize, LDS_BYTES);

        pack_fp8_kernel<<<N_COLS * NB_CAT / 256, 256, 0, stream>>>(
            (const float4*)cf, (uint4*)d_ws);

        IndexKernel_32238024524411_kernel<<<N_PAIRS / 4096, 1024, LDS_BYTES, stream>>>(
            (const int4*)x, (const int4*)y, (const uint4*)d_ws, stdv, out);
        return;
    }
#endif
    fallback_kernel<<<N_PAIRS / 32, 256, 0, stream>>>(
        x, y, (const float4*)cf, stdv, out);
}

// Round 17
// 90.314 us; speedup vs baseline: 1.2515x; 1.2515x over previous
//
#include <hip/hip_runtime.h>

#define NB_CAT  8192
#define RANK    16
#define N_COLS  4
#define N_PAIRS 1048576

#define SLICE_ROWS  NB_CAT
#define SLICE_BYTES (SLICE_ROWS * 16)               // 128 KB: 8192 rows x 16 fp8
#define TBL_BYTES   ((size_t)N_COLS * SLICE_BYTES)  // 512 KB
#define LDS_BYTES   SLICE_BYTES                     // single 128 KB buffer

typedef float float2v __attribute__((ext_vector_type(2)));

// Device-pass-only builtin detection (host pass lacks amdgcn builtins; host
// never executes device bodies, so its fallback body is irrelevant).
#if defined(__HIP_DEVICE_COMPILE__) && defined(__has_builtin)
#if __has_builtin(__builtin_amdgcn_cvt_pk_f32_fp8) && __has_builtin(__builtin_amdgcn_cvt_pk_fp8_f32)
#define DEV_FP8_HW 1
#endif
#endif

template <int C> __device__ __forceinline__ int comp(const int4& v) {
    if (C == 0) return v.x;
    if (C == 1) return v.y;
    if (C == 2) return v.z;
    return v.w;
}

// ---- e4m3fn software decode/encode (safety net; HW path used on gfx950) ----
__device__ __forceinline__ float sw_dec_fp8(unsigned int b) {
    const unsigned int s = b >> 7, e = (b >> 3) & 0xF, m = b & 7;
    float v;
    if (e == 0) v = (float)m * 0.001953125f;            // m * 2^-9
    else        v = ldexpf((float)(8 + m), (int)e - 10); // (1+m/8)*2^(e-7)
    return s ? -v : v;
}
__device__ __forceinline__ unsigned int sw_enc_fp8(float f) {
    const unsigned int s = (__float_as_uint(f) >> 31) << 7;
    float a = fabsf(f);
    if (a > 448.f) a = 448.f;
    float q;
    if (a >= 0.015625f) {            // normal range (>= 2^-6)
        int ex; const float m = frexpf(a, &ex);         // m in [0.5,1)
        q = ldexpf(rintf(ldexpf(m, 4)), ex - 4);
    } else {
        q = rintf(a * 512.f) * 0.001953125f;            // subnormal grid 2^-9
    }
    if (q == 0.f) return s;
    int ex; const float m = frexpf(q, &ex);             // q = m * 2^ex
    if (ex - 1 < -6) {                                  // subnormal
        const unsigned int mm = (unsigned int)rintf(q * 512.f);
        return s | (mm & 7);
    }
    const unsigned int e = (unsigned int)(ex - 1 + 7);
    const unsigned int mm = (unsigned int)rintf(ldexpf(m, 4)) & 7;
    return s | (e << 3) | mm;
}

// HI must be a compile-time constant: the builtin's selector operand requires
// an immediate (R16 compile failure — runtime bool param rejected).
template <bool HI>
__device__ __forceinline__ float2v dec2(unsigned int u) {
#ifdef DEV_FP8_HW
    return __builtin_amdgcn_cvt_pk_f32_fp8((int)u, HI);
#else
    const unsigned int w = HI ? (u >> 16) : u;
    float2v r;
    r.x = sw_dec_fp8(w & 0xFF);
    r.y = sw_dec_fp8((w >> 8) & 0xFF);
    return r;
#endif
}

__device__ __forceinline__ float dot16_fp8(uint4 A, uint4 B, float acc) {
#define TERM(u, v, SEL)                                                        \
    {                                                                          \
        const float2v a = dec2<SEL>((u));                                      \
        const float2v b = dec2<SEL>((v));                                      \
        acc = fmaf(a.x, b.x, acc);                                             \
        acc = fmaf(a.y, b.y, acc);                                             \
    }
    TERM(A.x, B.x, false) TERM(A.x, B.x, true)
    TERM(A.y, B.y, false) TERM(A.y, B.y, true)
    TERM(A.z, B.z, false) TERM(A.z, B.z, true)
    TERM(A.w, B.w, false) TERM(A.w, B.w, true)
#undef TERM
    return acc;
}

// ---------- prep: fp32 cf -> fp8 e4m3 table, [c][cat] row = 16 B ----------
__global__ __launch_bounds__(256) void pack_fp8_kernel(
    const float4* __restrict__ src, uint4* __restrict__ dst)
{
    const int r = blockIdx.x * 256 + threadIdx.x;   // c*NB_CAT + k, 32768 rows
    const float4 f0 = src[r * 4 + 0];
    const float4 f1 = src[r * 4 + 1];
    const float4 f2 = src[r * 4 + 2];
    const float4 f3 = src[r * 4 + 3];
    uint4 u;
#ifdef DEV_FP8_HW
    int w;
    w = 0;
    w = __builtin_amdgcn_cvt_pk_fp8_f32(f0.x, f0.y, w, false);
    w = __builtin_amdgcn_cvt_pk_fp8_f32(f0.z, f0.w, w, true);
    u.x = (unsigned int)w;
    w = 0;
    w = __builtin_amdgcn_cvt_pk_fp8_f32(f1.x, f1.y, w, false);
    w = __builtin_amdgcn_cvt_pk_fp8_f32(f1.z, f1.w, w, true);
    u.y = (unsigned int)w;
    w = 0;
    w = __builtin_amdgcn_cvt_pk_fp8_f32(f2.x, f2.y, w, false);
    w = __builtin_amdgcn_cvt_pk_fp8_f32(f2.z, f2.w, w, true);
    u.z = (unsigned int)w;
    w = 0;
    w = __builtin_amdgcn_cvt_pk_fp8_f32(f3.x, f3.y, w, false);
    w = __builtin_amdgcn_cvt_pk_fp8_f32(f3.z, f3.w, w, true);
    u.w = (unsigned int)w;
#else
    u.x = sw_enc_fp8(f0.x) | (sw_enc_fp8(f0.y) << 8) | (sw_enc_fp8(f0.z) << 16) | (sw_enc_fp8(f0.w) << 24);
    u.y = sw_enc_fp8(f1.x) | (sw_enc_fp8(f1.y) << 8) | (sw_enc_fp8(f1.z) << 16) | (sw_enc_fp8(f1.w) << 24);
    u.z = sw_enc_fp8(f2.x) | (sw_enc_fp8(f2.y) << 8) | (sw_enc_fp8(f2.z) << 16) | (sw_enc_fp8(f2.w) << 24);
    u.w = sw_enc_fp8(f3.x) | (sw_enc_fp8(f3.y) << 8) | (sw_enc_fp8(f3.z) << 16) | (sw_enc_fp8(f3.w) << 24);
#endif
    dst[r] = u;
}

// ---------- main: 4 phases (one per col), single buffer, named-reg prefetch ----------
// 256 blocks x 1024 threads, 128 KB dyn LDS. One 16-B row = whole rank-16 fp8
// vector -> per pair per phase: 2 ds_read_b128 + 16 cvt + 16 fma. Half the LDS
// instructions and half the staging of the fp16 structure (R12/R14).
__global__ __launch_bounds__(1024, 1) void IndexKernel_32238024524411_kernel(
    const int4*  __restrict__ x4,
    const int4*  __restrict__ y4,
    const uint4* __restrict__ tbl,   // fp8 table in ws
    const float* __restrict__ stdv,
    float*       __restrict__ out)
{
    extern __shared__ uint4 sh[];    // 8192 rows = 128 KB

    const int tid  = threadIdx.x;
    const int base = blockIdx.x * 4096 + tid;

    int4 xv[4], yv[4];
#pragma unroll
    for (int j = 0; j < 4; ++j) {
        xv[j] = x4[base + j * 1024];
        yv[j] = y4[base + j * 1024];
    }

    float acc[4] = {0.f, 0.f, 0.f, 0.f};

    // diagonal std^2 pre-pass (exact fp32)
#pragma unroll
    for (int j = 0; j < 4; ++j) {
        const int4 a = xv[j], b = yv[j];
        if (a.x == b.x) { const float s = stdv[0 * NB_CAT + a.x]; acc[j] = fmaf(s, s, acc[j]); }
        if (a.y == b.y) { const float s = stdv[1 * NB_CAT + a.y]; acc[j] = fmaf(s, s, acc[j]); }
        if (a.z == b.z) { const float s = stdv[2 * NB_CAT + a.z]; acc[j] = fmaf(s, s, acc[j]); }
        if (a.w == b.w) { const float s = stdv[3 * NB_CAT + a.w]; acc[j] = fmaf(s, s, acc[j]); }
    }

    // stage col-0 slice (direct copy, compiler temps only)
#pragma unroll
    for (int it = 0; it < 8; ++it) sh[tid + it * 1024] = tbl[tid + it * 1024];
    asm volatile("s_waitcnt lgkmcnt(0)" ::: "memory");
    __builtin_amdgcn_s_barrier();
    asm volatile("" ::: "memory");

    uint4 t0, t1, t2, t3, t4, t5, t6, t7;   // named prefetch regs (no array — R10 lesson)

#define PHASE(S)                                                               \
    {                                                                          \
        constexpr int s = (S);                                                 \
        if (s < N_COLS - 1) {                                                  \
            const uint4* nsrc = tbl + (size_t)(s + 1) * SLICE_ROWS;            \
            t0 = nsrc[tid];             t1 = nsrc[tid + 1024];                 \
            t2 = nsrc[tid + 2 * 1024];  t3 = nsrc[tid + 3 * 1024];             \
            t4 = nsrc[tid + 4 * 1024];  t5 = nsrc[tid + 5 * 1024];             \
            t6 = nsrc[tid + 6 * 1024];  t7 = nsrc[tid + 7 * 1024];             \
        }                                                                      \
        asm volatile("" ::: "memory");                                         \
        _Pragma("unroll")                                                      \
        for (int j = 0; j < 4; ++j) {                                          \
            const int a = comp<s>(xv[j]);                                      \
            const int b = comp<s>(yv[j]);                                      \
            acc[j] = dot16_fp8(sh[a], sh[b], acc[j]);                          \
        }                                                                      \
        if (s < N_COLS - 1) {                                                  \
            asm volatile("s_waitcnt lgkmcnt(0)" ::: "memory");                 \
            __builtin_amdgcn_s_barrier();                                      \
            asm volatile("" ::: "memory");                                     \
            sh[tid]            = t0;  sh[tid + 1024]     = t1;                 \
            sh[tid + 2 * 1024] = t2;  sh[tid + 3 * 1024] = t3;                 \
            sh[tid + 4 * 1024] = t4;  sh[tid + 5 * 1024] = t5;                 \
            sh[tid + 6 * 1024] = t6;  sh[tid + 7 * 1024] = t7;                 \
            asm volatile("s_waitcnt lgkmcnt(0)" ::: "memory");                 \
            __builtin_amdgcn_s_barrier();                                      \
            asm volatile("" ::: "memory");                                     \
        }                                                                      \
    }

    PHASE(0) PHASE(1) PHASE(2) PHASE(3)
#undef PHASE

#pragma unroll
    for (int j = 0; j < 4; ++j) {
        out[base + j * 1024] = acc[j];
    }
}

// ---------- fallback (fp32 direct gather, R3 structure) if ws too small ----------
__global__ __launch_bounds__(256) void fallback_kernel(
    const int* __restrict__ x, const int* __restrict__ y,
    const float4* __restrict__ cf, const float* __restrict__ stdv,
    float* __restrict__ out)
{
    const int tid = threadIdx.x;
    const int q = tid & 15, gi = tid >> 4, c = q >> 2, s = q & 3;
    const int p0 = blockIdx.x * 32 + gi, p1 = p0 + 16;
    const int rb = c * NB_CAT;
    const int xi0 = x[p0*4+c], yi0 = y[p0*4+c], xi1 = x[p1*4+c], yi1 = y[p1*4+c];
    const float4 a0 = cf[(size_t)(rb+xi0)*4 + s], b0 = cf[(size_t)(rb+yi0)*4 + s];
    const float4 a1 = cf[(size_t)(rb+xi1)*4 + s], b1 = cf[(size_t)(rb+yi1)*4 + s];
    float v0 = a0.x*b0.x; v0 = fmaf(a0.y,b0.y,v0); v0 = fmaf(a0.z,b0.z,v0); v0 = fmaf(a0.w,b0.w,v0);
    float v1 = a1.x*b1.x; v1 = fmaf(a1.y,b1.y,v1); v1 = fmaf(a1.z,b1.z,v1); v1 = fmaf(a1.w,b1.w,v1);
    if (s == 0 && xi0 == yi0) { float sd = stdv[rb+xi0]; v0 = fmaf(sd,sd,v0); }
    if (s == 0 && xi1 == yi1) { float sd = stdv[rb+yi1]; v1 = fmaf(sd,sd,v1); }
    int t;
    t = __builtin_amdgcn_update_dpp(0, __float_as_int(v0), 0xB1, 0xF, 0xF, true); v0 += __int_as_float(t);
    t = __builtin_amdgcn_update_dpp(0, __float_as_int(v0), 0x4E, 0xF, 0xF, true); v0 += __int_as_float(t);
    t = __builtin_amdgcn_update_dpp(0, __float_as_int(v0), 0x141,0xF, 0xF, true); v0 += __int_as_float(t);
    t = __builtin_amdgcn_update_dpp(0, __float_as_int(v0), 0x128,0xF, 0xF, true); v0 += __int_as_float(t);
    t = __builtin_amdgcn_update_dpp(0, __float_as_int(v1), 0xB1, 0xF, 0xF, true); v1 += __int_as_float(t);
    t = __builtin_amdgcn_update_dpp(0, __float_as_int(v1), 0x4E, 0xF, 0xF, true); v1 += __int_as_float(t);
    t = __builtin_amdgcn_update_dpp(0, __float_as_int(v1), 0x141,0xF, 0xF, true); v1 += __int_as_float(t);
    t = __builtin_amdgcn_update_dpp(0, __float_as_int(v1), 0x128,0xF, 0xF, true); v1 += __int_as_float(t);
    if (q == 0) { out[p0] = v0; out[p1] = v1; }
}

extern "C" void kernel_launch(void* const* d_in, const int* in_sizes, int n_in,
                              void* d_out, int out_size, void* d_ws, size_t ws_size,
                              hipStream_t stream) {
    const int*   x    = (const int*)d_in[0];
    const int*   y    = (const int*)d_in[1];
    const float* cf   = (const float*)d_in[2];
    const float* stdv = (const float*)d_in[3];
    float*       out  = (float*)d_out;

    // Host gating depends ONLY on ws_size (R15 lesson).
    if (ws_size < TBL_BYTES) {
        fallback_kernel<<<N_PAIRS / 32, 256, 0, stream>>>(
            x, y, (const float4*)cf, stdv, out);
        return;
    }

    (void)hipFuncSetAttribute(
        reinterpret_cast<const void*>(&IndexKernel_32238024524411_kernel),
        hipFuncAttributeMaxDynamicSharedMemorySize, LDS_BYTES);

    pack_fp8_kernel<<<N_COLS * NB_CAT / 256, 256, 0, stream>>>(
        (const float4*)cf, (uint4*)d_ws);

    IndexKernel_32238024524411_kernel<<<N_PAIRS / 4096, 1024, LDS_BYTES, stream>>>(
        (const int4*)x, (const int4*)y, (const uint4*)d_ws, stdv, out);
}